// Round 1
// baseline (313.309 us; speedup 1.0000x reference)
//
#include <hip/hip_runtime.h>
#include <hip/hip_bf16.h>

#define N_NODES 50000
#define N_EDGES 800000
#define IN_DIM  256
#define HID     128
#define LEAKY   0.01f

#define EDGE_BLOCKS  ((N_EDGES + 255) / 256)      // 3125
#define NODE_WBLKS   (N_NODES / 4)                // 12500
#define SCAN_BLOCKS  ((N_NODES + 255) / 256)      // 196
#define W1_ELEMS  (HID * IN_DIM)                  // 32768
#define W2_ELEMS  (HID * HID)                     // 16384

#define TM        64                              // GEMM rows per block
#define FC_BLOCKS ((N_NODES + TM - 1) / TM)       // 782

typedef __attribute__((ext_vector_type(8))) short short8;
typedef __attribute__((ext_vector_type(4))) float f32x4;

__device__ __forceinline__ unsigned short f2bf(float x) {
    union { __hip_bfloat16 b; unsigned short u; } c;
    c.b = __float2bfloat16(x);
    return c.u;
}
__device__ __forceinline__ float bf2f(unsigned short u) {
    union { unsigned int u; float f; } c;
    c.u = ((unsigned int)u) << 16;
    return c.f;
}
__device__ __forceinline__ float2 bfu2(unsigned int u) {
    float2 r;
    r.x = bf2f((unsigned short)(u & 0xffff));
    r.y = bf2f((unsigned short)(u >> 16));
    return r;
}
__device__ __forceinline__ float lky(float x) { return x > 0.f ? x : LEAKY * x; }
__device__ __forceinline__ float rl_f(float v, int l) {
    return __int_as_float(__builtin_amdgcn_readlane(__float_as_int(v), l));
}

// split 8 fp32 into bf16 hi/lo planes (same op order as previous LDS-staged version)
__device__ __forceinline__ void cvt8(const float4 v0, const float4 v1,
                                     short8& hi, short8& lo) {
    float f[8] = {v0.x, v0.y, v0.z, v0.w, v1.x, v1.y, v1.z, v1.w};
#pragma unroll
    for (int j = 0; j < 8; j++) {
        unsigned short h = f2bf(f[j]);
        hi[j] = (short)h;
        lo[j] = (short)f2bf(f[j] - bf2f(h));
    }
}

// ------- CSR hist (rank-returning) + W splits (fused, independent work) --------

__global__ void hist_split(const int* __restrict__ dst, int* __restrict__ counts,
                           int* __restrict__ erank,
                           const float* __restrict__ W1, unsigned short* __restrict__ w1hi,
                           unsigned short* __restrict__ w1lo,
                           const float* __restrict__ W2, unsigned short* __restrict__ w2hi,
                           unsigned short* __restrict__ w2lo) {
    int i = blockIdx.x * 256 + threadIdx.x;
    if (i < N_EDGES) erank[i] = atomicAdd(&counts[dst[i]], 1);
    if (i < W1_ELEMS) {
        float x = W1[i];
        unsigned short h = f2bf(x);
        w1hi[i] = h;
        w1lo[i] = f2bf(x - bf2f(h));
    } else if (i < W1_ELEMS + W2_ELEMS) {
        int j = i - W1_ELEMS;
        float x = W2[j];
        unsigned short h = f2bf(x);
        w2hi[j] = h;
        w2lo[j] = f2bf(x - bf2f(h));
    }
}

__global__ void scan_block(const int* __restrict__ counts, int* __restrict__ offsets,
                           int* __restrict__ bsums) {
    __shared__ int sh[256];
    int tid = threadIdx.x;
    int i = blockIdx.x * 256 + tid;
    int v = (i < N_NODES) ? counts[i] : 0;
    sh[tid] = v;
    __syncthreads();
    for (int o = 1; o < 256; o <<= 1) {
        int t = (tid >= o) ? sh[tid - o] : 0;
        __syncthreads();
        sh[tid] += t;
        __syncthreads();
    }
    if (i < N_NODES) offsets[i] = sh[tid] - v;
    if (tid == 255) bsums[blockIdx.x] = sh[255];
}

__global__ void scan_add(int* __restrict__ offsets, const int* __restrict__ bsums) {
    __shared__ int sh[256];
    int tid = threadIdx.x;
    int b = blockIdx.x;
    sh[tid] = (tid < b) ? bsums[tid] : 0;   // b <= 195 < 256
    __syncthreads();
    for (int o = 128; o > 0; o >>= 1) {
        if (tid < o) sh[tid] += sh[tid + o];
        __syncthreads();
    }
    int base = sh[0];
    int i = b * 256 + tid;
    if (i < N_NODES) offsets[i] += base;
    if (i == N_NODES) offsets[N_NODES] = N_EDGES;
}

// fill: atomic-free scatter; nontemporal store avoids cross-XCD L2 line bounce
__global__ void fill_kernel(const int* __restrict__ dst, const int* __restrict__ src,
                            const int* __restrict__ erank,
                            const int* __restrict__ offsets,
                            int* __restrict__ csr_src) {
    int i = blockIdx.x * 256 + threadIdx.x;
    if (i < N_EDGES) {
        int d = dst[i];
        int slot = offsets[d] + erank[i];
        __builtin_nontemporal_store(src[i], &csr_src[slot]);
    }
}

// ---------------- epilogue for one 16-row subtile ----------------
// C/D: col = lane&15, row = (lane>>4)*4 + reg. Partial scores reduce over r
// via shfl_xor, then land in sbuf[q*128 + {0:S,64:D} + lrow] for block-combine.

__device__ __forceinline__ void epi(const f32x4* accn, int lrow0, int m0, int q, int lane,
                                    const float* __restrict__ bias,
                                    const float* __restrict__ attn,
                                    unsigned short* __restrict__ Zb,
                                    float* __restrict__ sbuf) {
    int r = lane & 15;
    int lrowbase = lrow0 + (lane >> 4) * 4;   // 0..63 within block
    float ps[4] = {0.f, 0.f, 0.f, 0.f};
    float pd[4] = {0.f, 0.f, 0.f, 0.f};
#pragma unroll
    for (int nt = 0; nt < 4; nt++) {
        int n = q * 64 + nt * 16 + r;
        float bn = bias[n];
        float aS = attn[n];
        float aD = attn[HID + n];
#pragma unroll
        for (int reg = 0; reg < 4; reg++) {
            float zv = accn[nt][reg] + bn;
            if (m0 + lrowbase + reg < N_NODES)
                Zb[(size_t)(m0 + lrowbase + reg) * HID + n] = f2bf(zv);
            ps[reg] += zv * aS;
            pd[reg] += zv * aD;
        }
    }
#pragma unroll
    for (int o = 1; o < 16; o <<= 1) {
#pragma unroll
        for (int reg = 0; reg < 4; reg++) {
            ps[reg] += __shfl_xor(ps[reg], o, 64);
            pd[reg] += __shfl_xor(pd[reg], o, 64);
        }
    }
    if (r == 0) {
#pragma unroll
        for (int reg = 0; reg < 4; reg++) {
            sbuf[q * 128 + lrowbase + reg] = ps[reg];
            sbuf[q * 128 + 64 + lrowbase + reg] = pd[reg];
        }
    }
}

// combine q-halves and store single score planes
__device__ __forceinline__ void score_combine(const float* __restrict__ sbuf, int tid, int m0,
                                              float* __restrict__ sS, float* __restrict__ sD) {
    if (tid < TM) {
        int gr = m0 + tid;
        if (gr < N_NODES) {
            sS[gr] = sbuf[tid] + sbuf[128 + tid];
            sD[gr] = sbuf[64 + tid] + sbuf[128 + 64 + tid];
        }
    }
}

// ------- FC1: LDS-free, register-direct fragments. Block = 64 rows x 128 cols. -------
// Each wave owns 32 rows x 64 cols. A frags load fp32 from global (full 64B-line
// consumption: lane-group g covers bytes [32g,32g+32) of its row), split to bf16
// hi/lo in-register. B frags load bf16 direct from the pre-split W planes
// (L2-resident, shared by all blocks). No LDS, no barriers in the K-loop.

__launch_bounds__(256, 3)
__global__ void gemm_fc1(const float* __restrict__ A,
                         const unsigned short* __restrict__ Whi,
                         const unsigned short* __restrict__ Wlo,
                         const float* __restrict__ bias,
                         const float* __restrict__ attn,
                         unsigned short* __restrict__ Zb,
                         float* __restrict__ sS, float* __restrict__ sD) {
    __shared__ float sbuf[256];

    int tid  = threadIdx.x;
    int lane = tid & 63;
    int w    = tid >> 6;
    int q    = w & 1;
    int mh   = w >> 1;
    int m0   = blockIdx.x * TM;
    int r    = lane & 15;
    int koff = (lane >> 4) * 8;

    const float* Ap[2];
#pragma unroll
    for (int s = 0; s < 2; s++) {
        int gr = m0 + mh * 32 + s * 16 + r;
        if (gr >= N_NODES) gr = N_NODES - 1;
        Ap[s] = A + (size_t)gr * IN_DIM + koff;
    }
    const unsigned short* Bph = Whi + (size_t)(q * 64 + r) * IN_DIM + koff;
    const unsigned short* Bpl = Wlo + (size_t)(q * 64 + r) * IN_DIM + koff;

    f32x4 acc[2][4];
#pragma unroll
    for (int s = 0; s < 2; s++)
#pragma unroll
        for (int nt = 0; nt < 4; nt++) acc[s][nt] = (f32x4){0.f, 0.f, 0.f, 0.f};

#pragma unroll 2
    for (int kt = 0; kt < IN_DIM / 32; kt++) {
        int k0 = kt * 32;
        short8 ah[2], al[2], bh[4], bl[4];
#pragma unroll
        for (int nt = 0; nt < 4; nt++) {
            bh[nt] = *(const short8*)(Bph + (size_t)nt * 16 * IN_DIM + k0);
            bl[nt] = *(const short8*)(Bpl + (size_t)nt * 16 * IN_DIM + k0);
        }
#pragma unroll
        for (int s = 0; s < 2; s++) {
            float4 v0 = *(const float4*)(Ap[s] + k0);
            float4 v1 = *(const float4*)(Ap[s] + k0 + 4);
            cvt8(v0, v1, ah[s], al[s]);
        }
#pragma unroll
        for (int s = 0; s < 2; s++)
#pragma unroll
            for (int nt = 0; nt < 4; nt++) {
                acc[s][nt] = __builtin_amdgcn_mfma_f32_16x16x32_bf16(ah[s], bh[nt], acc[s][nt], 0, 0, 0);
                acc[s][nt] = __builtin_amdgcn_mfma_f32_16x16x32_bf16(al[s], bh[nt], acc[s][nt], 0, 0, 0);
                acc[s][nt] = __builtin_amdgcn_mfma_f32_16x16x32_bf16(ah[s], bl[nt], acc[s][nt], 0, 0, 0);
            }
    }

#pragma unroll
    for (int s = 0; s < 2; s++)
        epi(acc[s], mh * 32 + s * 16, m0, q, lane, bias, attn, Zb, sbuf);
    __syncthreads();
    score_combine(sbuf, tid, m0, sS, sD);
}

// ------- FC2: same structure; A = h1 (single bf16 plane), W2 hi/lo. ----

__launch_bounds__(256, 3)
__global__ void gemm_fc2(const unsigned short* __restrict__ Abf,
                         const unsigned short* __restrict__ Whi,
                         const unsigned short* __restrict__ Wlo,
                         const float* __restrict__ bias,
                         const float* __restrict__ attn,
                         unsigned short* __restrict__ Zb,
                         float* __restrict__ sS, float* __restrict__ sD) {
    __shared__ float sbuf[256];

    int tid  = threadIdx.x;
    int lane = tid & 63;
    int w    = tid >> 6;
    int q    = w & 1;
    int mh   = w >> 1;
    int m0   = blockIdx.x * TM;
    int r    = lane & 15;
    int koff = (lane >> 4) * 8;

    const unsigned short* Ap[2];
#pragma unroll
    for (int s = 0; s < 2; s++) {
        int gr = m0 + mh * 32 + s * 16 + r;
        if (gr >= N_NODES) gr = N_NODES - 1;
        Ap[s] = Abf + (size_t)gr * HID + koff;
    }
    const unsigned short* Bph = Whi + (size_t)(q * 64 + r) * HID + koff;
    const unsigned short* Bpl = Wlo + (size_t)(q * 64 + r) * HID + koff;

    f32x4 acc[2][4];
#pragma unroll
    for (int s = 0; s < 2; s++)
#pragma unroll
        for (int nt = 0; nt < 4; nt++) acc[s][nt] = (f32x4){0.f, 0.f, 0.f, 0.f};

#pragma unroll 2
    for (int kt = 0; kt < HID / 32; kt++) {
        int k0 = kt * 32;
        short8 ah[2], bh[4], bl[4];
#pragma unroll
        for (int nt = 0; nt < 4; nt++) {
            bh[nt] = *(const short8*)(Bph + (size_t)nt * 16 * HID + k0);
            bl[nt] = *(const short8*)(Bpl + (size_t)nt * 16 * HID + k0);
        }
#pragma unroll
        for (int s = 0; s < 2; s++)
            ah[s] = *(const short8*)(Ap[s] + k0);
#pragma unroll
        for (int s = 0; s < 2; s++)
#pragma unroll
            for (int nt = 0; nt < 4; nt++) {
                acc[s][nt] = __builtin_amdgcn_mfma_f32_16x16x32_bf16(ah[s], bh[nt], acc[s][nt], 0, 0, 0);
                acc[s][nt] = __builtin_amdgcn_mfma_f32_16x16x32_bf16(ah[s], bl[nt], acc[s][nt], 0, 0, 0);
            }
    }

#pragma unroll
    for (int s = 0; s < 2; s++)
        epi(acc[s], mh * 32 + s * 16, m0, q, lane, bias, attn, Zb, sbuf);
    __syncthreads();
    score_combine(sbuf, tid, m0, sS, sD);
}

// ---------------- segment softmax + weighted gather-sum + ELU ----------------
// one wave per dst node. Fast path: per-edge (src, alpha) in lane registers;
// phase C broadcasts via v_readlane (scalar pipe, no LDS), 16-deep MLP batches.

template <int OUT_BF>
__launch_bounds__(256)
__global__ void aggregate(const unsigned short* __restrict__ Zb,
                          const int* __restrict__ csr_src,
                          const int* __restrict__ offsets,
                          const float* __restrict__ sS,
                          const float* __restrict__ sD,
                          const float* __restrict__ ab,
                          unsigned short* __restrict__ OutBf,
                          float* __restrict__ OutF) {
    int v = blockIdx.x * 4 + (threadIdx.x >> 6);
    int lane = threadIdx.x & 63;
    int off = offsets[v];
    int deg = offsets[v + 1] - off;
    float sdv = sD[v] + ab[0];

    const unsigned int* Zrow = (const unsigned int*)Zb;  // dword = 2 bf16 dims
    float2 acc = {0.f, 0.f};

    if (deg <= 64) {
        bool act = lane < deg;
        int s_l = 0;
        float x = -3.0e38f;
        if (act) {
            s_l = csr_src[off + lane];
            x = lky(sS[s_l] + sdv);
        }
        float mx = x;
#pragma unroll
        for (int o = 32; o > 0; o >>= 1) mx = fmaxf(mx, __shfl_xor(mx, o, 64));
        float ex = act ? __expf(x - mx) : 0.f;
        float sum = ex;
#pragma unroll
        for (int o = 32; o > 0; o >>= 1) sum += __shfl_xor(sum, o, 64);
        float al_l = (deg > 0) ? ex / sum : 0.f;

        int t = 0;
        for (; t + 16 <= deg; t += 16) {
            int   s[16];
            float a[16];
            unsigned int rw[16];
#pragma unroll
            for (int j = 0; j < 16; j++) {
                s[j] = __builtin_amdgcn_readlane(s_l, t + j);
                a[j] = rl_f(al_l, t + j);
            }
#pragma unroll
            for (int j = 0; j < 16; j++)
                rw[j] = Zrow[(size_t)s[j] * (HID / 2) + lane];
#pragma unroll
            for (int j = 0; j < 16; j++) {
                float2 zz = bfu2(rw[j]);
                acc.x += a[j] * zz.x;
                acc.y += a[j] * zz.y;
            }
        }
        for (; t + 4 <= deg; t += 4) {
            int   s[4];
            float a[4];
            unsigned int rw[4];
#pragma unroll
            for (int j = 0; j < 4; j++) {
                s[j] = __builtin_amdgcn_readlane(s_l, t + j);
                a[j] = rl_f(al_l, t + j);
            }
#pragma unroll
            for (int j = 0; j < 4; j++)
                rw[j] = Zrow[(size_t)s[j] * (HID / 2) + lane];
#pragma unroll
            for (int j = 0; j < 4; j++) {
                float2 zz = bfu2(rw[j]);
                acc.x += a[j] * zz.x;
                acc.y += a[j] * zz.y;
            }
        }
        for (; t < deg; t++) {
            int sj = __builtin_amdgcn_readlane(s_l, t);
            float aj = rl_f(al_l, t);
            float2 zz = bfu2(Zrow[(size_t)sj * (HID / 2) + lane]);
            acc.x += aj * zz.x;
            acc.y += aj * zz.y;
        }
    } else {
        float mx = -3.0e38f;
        for (int t = lane; t < deg; t += 64) {
            int s = csr_src[off + t];
            mx = fmaxf(mx, lky(sS[s] + sdv));
        }
#pragma unroll
        for (int o = 32; o > 0; o >>= 1) mx = fmaxf(mx, __shfl_xor(mx, o, 64));
        float sum = 0.f;
        for (int t = lane; t < deg; t += 64) {
            int s = csr_src[off + t];
            sum += __expf(lky(sS[s] + sdv) - mx);
        }
#pragma unroll
        for (int o = 32; o > 0; o >>= 1) sum += __shfl_xor(sum, o, 64);
        float inv = 1.f / sum;
        for (int t = 0; t < deg; t++) {
            int s = csr_src[off + t];
            float al = __expf(lky(sS[s] + sdv) - mx) * inv;
            float2 zz = bfu2(Zrow[(size_t)s * (HID / 2) + lane]);
            acc.x += al * zz.x;
            acc.y += al * zz.y;
        }
    }

    acc.x = acc.x > 0.f ? acc.x : __expf(acc.x) - 1.f;
    acc.y = acc.y > 0.f ? acc.y : __expf(acc.y) - 1.f;

    if (OUT_BF) {
        ushort2 o2;
        o2.x = f2bf(acc.x);
        o2.y = f2bf(acc.y);
        *((ushort2*)(OutBf + (size_t)v * HID + lane * 2)) = o2;
    } else {
        float2 o2 = {acc.x, acc.y};
        *((float2*)(OutF + (size_t)v * HID + lane * 2)) = o2;
    }
}

// ---------------- launch ----------------

extern "C" void kernel_launch(void* const* d_in, const int* in_sizes, int n_in,
                              void* d_out, int out_size, void* d_ws, size_t ws_size,
                              hipStream_t stream) {
    const float* h   = (const float*)d_in[0];
    const int*   src = (const int*)d_in[1];
    const int*   dst = (const int*)d_in[2];
    const float* W1  = (const float*)d_in[3];
    const float* b1  = (const float*)d_in[4];
    const float* a1  = (const float*)d_in[5];
    const float* ab1 = (const float*)d_in[6];
    const float* W2  = (const float*)d_in[7];
    const float* b2  = (const float*)d_in[8];
    const float* a2  = (const float*)d_in[9];
    const float* ab2 = (const float*)d_in[10];
    float* out = (float*)d_out;

    // workspace carve-up (~34 MB)
    unsigned short* zb = (unsigned short*)d_ws;                 // 50000*128 bf16
    float* sS = (float*)(zb + (size_t)N_NODES * HID);           // 50000 f32
    float* sD = sS + N_NODES;                                   // 50000 f32
    int* counts  = (int*)(sD + N_NODES);                        // 50000
    int* offsets = counts + N_NODES;                            // 50001 (+pad)
    int* bsums   = offsets + N_NODES + 16;                      // 256
    unsigned short* h1   = (unsigned short*)(bsums + 256);      // 50000*128 bf16
    unsigned short* w1hi = h1 + (size_t)N_NODES * HID;          // 32768
    unsigned short* w1lo = w1hi + W1_ELEMS;
    unsigned short* w2hi = w1lo + W1_ELEMS;                     // 16384
    unsigned short* w2lo = w2hi + W2_ELEMS;
    int* csr_src = (int*)(w2lo + W2_ELEMS);                     // 800000
    int* erank   = csr_src + N_EDGES;                           // 800000

    hipMemsetAsync(counts, 0, (size_t)N_NODES * sizeof(int), stream);

    // CSR by dst + weight splits; hist returns each edge's in-bucket rank
    hist_split<<<EDGE_BLOCKS, 256, 0, stream>>>(dst, counts, erank,
                                                W1, w1hi, w1lo, W2, w2hi, w2lo);
    scan_block<<<SCAN_BLOCKS, 256, 0, stream>>>(counts, offsets, bsums);
    scan_add<<<SCAN_BLOCKS, 256, 0, stream>>>(offsets, bsums);
    fill_kernel<<<EDGE_BLOCKS, 256, 0, stream>>>(dst, src, erank, offsets, csr_src);

    // layer 1
    gemm_fc1<<<FC_BLOCKS, 256, 0, stream>>>(h, w1hi, w1lo, b1, a1, zb, sS, sD);
    aggregate<1><<<NODE_WBLKS, 256, 0, stream>>>(zb, csr_src, offsets, sS, sD, ab1, h1, nullptr);

    // layer 2
    gemm_fc2<<<FC_BLOCKS, 256, 0, stream>>>(h1, w2hi, w2lo, b2, a2, zb, sS, sD);
    aggregate<0><<<NODE_WBLKS, 256, 0, stream>>>(zb, csr_src, offsets, sS, sD, ab2, nullptr, out);
}

// Round 2
// 310.918 us; speedup vs baseline: 1.0077x; 1.0077x over previous
//
#include <hip/hip_runtime.h>
#include <hip/hip_bf16.h>

#define N_NODES 50000
#define N_EDGES 800000
#define IN_DIM  256
#define HID     128
#define LEAKY   0.01f

#define EDGE_BLOCKS  ((N_EDGES + 255) / 256)      // 3125
#define NODE_WBLKS   (N_NODES / 4)                // 12500
#define SCAN_BLOCKS  ((N_NODES + 255) / 256)      // 196
#define W1_ELEMS  (HID * IN_DIM)                  // 32768
#define W2_ELEMS  (HID * HID)                     // 16384

#define TM        64                              // GEMM rows per block
#define FC_BLOCKS ((N_NODES + TM - 1) / TM)       // 782

typedef __attribute__((ext_vector_type(8))) short short8;
typedef __attribute__((ext_vector_type(4))) float f32x4;

__device__ __forceinline__ unsigned short f2bf(float x) {
    union { __hip_bfloat16 b; unsigned short u; } c;
    c.b = __float2bfloat16(x);
    return c.u;
}
__device__ __forceinline__ float bf2f(unsigned short u) {
    union { unsigned int u; float f; } c;
    c.u = ((unsigned int)u) << 16;
    return c.f;
}
__device__ __forceinline__ float2 bfu2(unsigned int u) {
    float2 r;
    r.x = bf2f((unsigned short)(u & 0xffff));
    r.y = bf2f((unsigned short)(u >> 16));
    return r;
}
__device__ __forceinline__ float lky(float x) { return x > 0.f ? x : LEAKY * x; }
__device__ __forceinline__ float rl_f(float v, int l) {
    return __int_as_float(__builtin_amdgcn_readlane(__float_as_int(v), l));
}

// split 8 fp32 into bf16 hi/lo planes (same op order as LDS-staged original)
__device__ __forceinline__ void cvt8(const float4 v0, const float4 v1,
                                     short8& hi, short8& lo) {
    float f[8] = {v0.x, v0.y, v0.z, v0.w, v1.x, v1.y, v1.z, v1.w};
#pragma unroll
    for (int j = 0; j < 8; j++) {
        unsigned short h = f2bf(f[j]);
        hi[j] = (short)h;
        lo[j] = (short)f2bf(f[j] - bf2f(h));
    }
}

// ------- CSR hist (rank-returning) + W splits (fused, independent work) --------

__global__ void hist_split(const int* __restrict__ dst, int* __restrict__ counts,
                           int* __restrict__ erank,
                           const float* __restrict__ W1, unsigned short* __restrict__ w1hi,
                           unsigned short* __restrict__ w1lo,
                           const float* __restrict__ W2, unsigned short* __restrict__ w2hi,
                           unsigned short* __restrict__ w2lo) {
    int i = blockIdx.x * 256 + threadIdx.x;
    if (i < N_EDGES) erank[i] = atomicAdd(&counts[dst[i]], 1);
    if (i < W1_ELEMS) {
        float x = W1[i];
        unsigned short h = f2bf(x);
        w1hi[i] = h;
        w1lo[i] = f2bf(x - bf2f(h));
    } else if (i < W1_ELEMS + W2_ELEMS) {
        int j = i - W1_ELEMS;
        float x = W2[j];
        unsigned short h = f2bf(x);
        w2hi[j] = h;
        w2lo[j] = f2bf(x - bf2f(h));
    }
}

__global__ void scan_block(const int* __restrict__ counts, int* __restrict__ offsets,
                           int* __restrict__ bsums) {
    __shared__ int sh[256];
    int tid = threadIdx.x;
    int i = blockIdx.x * 256 + tid;
    int v = (i < N_NODES) ? counts[i] : 0;
    sh[tid] = v;
    __syncthreads();
    for (int o = 1; o < 256; o <<= 1) {
        int t = (tid >= o) ? sh[tid - o] : 0;
        __syncthreads();
        sh[tid] += t;
        __syncthreads();
    }
    if (i < N_NODES) offsets[i] = sh[tid] - v;
    if (tid == 255) bsums[blockIdx.x] = sh[255];
}

__global__ void scan_add(int* __restrict__ offsets, const int* __restrict__ bsums) {
    __shared__ int sh[256];
    int tid = threadIdx.x;
    int b = blockIdx.x;
    sh[tid] = (tid < b) ? bsums[tid] : 0;   // b <= 195 < 256
    __syncthreads();
    for (int o = 128; o > 0; o >>= 1) {
        if (tid < o) sh[tid] += sh[tid + o];
        __syncthreads();
    }
    int base = sh[0];
    int i = b * 256 + tid;
    if (i < N_NODES) offsets[i] += base;
    if (i == N_NODES) offsets[N_NODES] = N_EDGES;
}

// fill: atomic-free scatter; nontemporal store avoids cross-XCD L2 line bounce
__global__ void fill_kernel(const int* __restrict__ dst, const int* __restrict__ src,
                            const int* __restrict__ erank,
                            const int* __restrict__ offsets,
                            int* __restrict__ csr_src) {
    int i = blockIdx.x * 256 + threadIdx.x;
    if (i < N_EDGES) {
        int d = dst[i];
        int slot = offsets[d] + erank[i];
        __builtin_nontemporal_store(src[i], &csr_src[slot]);
    }
}

// ---------------- epilogue for one 16-row subtile ----------------
// C/D: col = lane&15, row = (lane>>4)*4 + reg. Partial scores reduce over r
// via shfl_xor, then land in sbuf[q*128 + {0:S,64:D} + lrow] for block-combine.

__device__ __forceinline__ void epi(const f32x4* accn, int lrow0, int m0, int q, int lane,
                                    const float* __restrict__ bias,
                                    const float* __restrict__ attn,
                                    unsigned short* __restrict__ Zb,
                                    float* __restrict__ sbuf) {
    int r = lane & 15;
    int lrowbase = lrow0 + (lane >> 4) * 4;   // 0..63 within block
    float ps[4] = {0.f, 0.f, 0.f, 0.f};
    float pd[4] = {0.f, 0.f, 0.f, 0.f};
#pragma unroll
    for (int nt = 0; nt < 4; nt++) {
        int n = q * 64 + nt * 16 + r;
        float bn = bias[n];
        float aS = attn[n];
        float aD = attn[HID + n];
#pragma unroll
        for (int reg = 0; reg < 4; reg++) {
            float zv = accn[nt][reg] + bn;
            if (m0 + lrowbase + reg < N_NODES)
                Zb[(size_t)(m0 + lrowbase + reg) * HID + n] = f2bf(zv);
            ps[reg] += zv * aS;
            pd[reg] += zv * aD;
        }
    }
#pragma unroll
    for (int o = 1; o < 16; o <<= 1) {
#pragma unroll
        for (int reg = 0; reg < 4; reg++) {
            ps[reg] += __shfl_xor(ps[reg], o, 64);
            pd[reg] += __shfl_xor(pd[reg], o, 64);
        }
    }
    if (r == 0) {
#pragma unroll
        for (int reg = 0; reg < 4; reg++) {
            sbuf[q * 128 + lrowbase + reg] = ps[reg];
            sbuf[q * 128 + 64 + lrowbase + reg] = pd[reg];
        }
    }
}

// combine q-halves and store single score planes
__device__ __forceinline__ void score_combine(const float* __restrict__ sbuf, int tid, int m0,
                                              float* __restrict__ sS, float* __restrict__ sD) {
    if (tid < TM) {
        int gr = m0 + tid;
        if (gr < N_NODES) {
            sS[gr] = sbuf[tid] + sbuf[128 + tid];
            sD[gr] = sbuf[64 + tid] + sbuf[128 + 64 + tid];
        }
    }
}

// ------- FC1: LDS-free, register-direct fragments, explicit 2-deep register
// double-buffer: iteration k+1's A (fp32, L3) and B (bf16 planes, L2) loads are
// issued BEFORE iteration k's convert+MFMA, so ~12 loads stay in flight under
// the 24-MFMA compute phase. All buffer indices compile-time (full unroll). -------

__launch_bounds__(256, 3)
__global__ void gemm_fc1(const float* __restrict__ A,
                         const unsigned short* __restrict__ Whi,
                         const unsigned short* __restrict__ Wlo,
                         const float* __restrict__ bias,
                         const float* __restrict__ attn,
                         unsigned short* __restrict__ Zb,
                         float* __restrict__ sS, float* __restrict__ sD) {
    __shared__ float sbuf[256];

    int tid  = threadIdx.x;
    int lane = tid & 63;
    int w    = tid >> 6;
    int q    = w & 1;
    int mh   = w >> 1;
    int m0   = blockIdx.x * TM;
    int r    = lane & 15;
    int koff = (lane >> 4) * 8;

    const float* Ap[2];
#pragma unroll
    for (int s = 0; s < 2; s++) {
        int gr = m0 + mh * 32 + s * 16 + r;
        if (gr >= N_NODES) gr = N_NODES - 1;
        Ap[s] = A + (size_t)gr * IN_DIM + koff;
    }
    const unsigned short* Bph = Whi + (size_t)(q * 64 + r) * IN_DIM + koff;
    const unsigned short* Bpl = Wlo + (size_t)(q * 64 + r) * IN_DIM + koff;

    f32x4 acc[2][4];
#pragma unroll
    for (int s = 0; s < 2; s++)
#pragma unroll
        for (int nt = 0; nt < 4; nt++) acc[s][nt] = (f32x4){0.f, 0.f, 0.f, 0.f};

    // register double-buffers (indices always compile-time constants)
    float4 av[2][2][2];            // [buf][s][half]
    short8 bh[2][4], bl[2][4];     // [buf][nt]

#define LOADA1(kt, pb)                                                      \
    {                                                                       \
        _Pragma("unroll") for (int s = 0; s < 2; s++) {                     \
            av[pb][s][0] = *(const float4*)(Ap[s] + (kt) * 32);             \
            av[pb][s][1] = *(const float4*)(Ap[s] + (kt) * 32 + 4);         \
        }                                                                   \
    }
#define LOADB1(kt, pb)                                                      \
    {                                                                       \
        _Pragma("unroll") for (int nt = 0; nt < 4; nt++) {                  \
            bh[pb][nt] = *(const short8*)(Bph + (size_t)nt * 16 * IN_DIM + (kt) * 32); \
            bl[pb][nt] = *(const short8*)(Bpl + (size_t)nt * 16 * IN_DIM + (kt) * 32); \
        }                                                                   \
    }

    LOADA1(0, 0);
    LOADB1(0, 0);

#pragma unroll
    for (int kt = 0; kt < IN_DIM / 32; kt++) {
        const int cur = kt & 1;
        const int nxt = cur ^ 1;
        if (kt < IN_DIM / 32 - 1) {
            LOADA1(kt + 1, nxt);
            LOADB1(kt + 1, nxt);
        }
        short8 ah[2], al[2];
#pragma unroll
        for (int s = 0; s < 2; s++) cvt8(av[cur][s][0], av[cur][s][1], ah[s], al[s]);
#pragma unroll
        for (int s = 0; s < 2; s++)
#pragma unroll
            for (int nt = 0; nt < 4; nt++) {
                acc[s][nt] = __builtin_amdgcn_mfma_f32_16x16x32_bf16(ah[s], bh[cur][nt], acc[s][nt], 0, 0, 0);
                acc[s][nt] = __builtin_amdgcn_mfma_f32_16x16x32_bf16(al[s], bh[cur][nt], acc[s][nt], 0, 0, 0);
                acc[s][nt] = __builtin_amdgcn_mfma_f32_16x16x32_bf16(ah[s], bl[cur][nt], acc[s][nt], 0, 0, 0);
            }
    }
#undef LOADA1
#undef LOADB1

#pragma unroll
    for (int s = 0; s < 2; s++)
        epi(acc[s], mh * 32 + s * 16, m0, q, lane, bias, attn, Zb, sbuf);
    __syncthreads();
    score_combine(sbuf, tid, m0, sS, sD);
}

// ------- FC2: same structure; A = h1 (single bf16 plane), W2 hi/lo. ----

__launch_bounds__(256, 3)
__global__ void gemm_fc2(const unsigned short* __restrict__ Abf,
                         const unsigned short* __restrict__ Whi,
                         const unsigned short* __restrict__ Wlo,
                         const float* __restrict__ bias,
                         const float* __restrict__ attn,
                         unsigned short* __restrict__ Zb,
                         float* __restrict__ sS, float* __restrict__ sD) {
    __shared__ float sbuf[256];

    int tid  = threadIdx.x;
    int lane = tid & 63;
    int w    = tid >> 6;
    int q    = w & 1;
    int mh   = w >> 1;
    int m0   = blockIdx.x * TM;
    int r    = lane & 15;
    int koff = (lane >> 4) * 8;

    const unsigned short* Ap[2];
#pragma unroll
    for (int s = 0; s < 2; s++) {
        int gr = m0 + mh * 32 + s * 16 + r;
        if (gr >= N_NODES) gr = N_NODES - 1;
        Ap[s] = Abf + (size_t)gr * HID + koff;
    }
    const unsigned short* Bph = Whi + (size_t)(q * 64 + r) * HID + koff;
    const unsigned short* Bpl = Wlo + (size_t)(q * 64 + r) * HID + koff;

    f32x4 acc[2][4];
#pragma unroll
    for (int s = 0; s < 2; s++)
#pragma unroll
        for (int nt = 0; nt < 4; nt++) acc[s][nt] = (f32x4){0.f, 0.f, 0.f, 0.f};

    short8 a8[2][2];               // [buf][s]
    short8 bh[2][4], bl[2][4];     // [buf][nt]

#define LOADA2(kt, pb)                                                      \
    {                                                                       \
        _Pragma("unroll") for (int s = 0; s < 2; s++)                       \
            a8[pb][s] = *(const short8*)(Ap[s] + (kt) * 32);                \
    }
#define LOADB2(kt, pb)                                                      \
    {                                                                       \
        _Pragma("unroll") for (int nt = 0; nt < 4; nt++) {                  \
            bh[pb][nt] = *(const short8*)(Bph + (size_t)nt * 16 * HID + (kt) * 32); \
            bl[pb][nt] = *(const short8*)(Bpl + (size_t)nt * 16 * HID + (kt) * 32); \
        }                                                                   \
    }

    LOADA2(0, 0);
    LOADB2(0, 0);

#pragma unroll
    for (int kt = 0; kt < HID / 32; kt++) {
        const int cur = kt & 1;
        const int nxt = cur ^ 1;
        if (kt < HID / 32 - 1) {
            LOADA2(kt + 1, nxt);
            LOADB2(kt + 1, nxt);
        }
#pragma unroll
        for (int s = 0; s < 2; s++)
#pragma unroll
            for (int nt = 0; nt < 4; nt++) {
                acc[s][nt] = __builtin_amdgcn_mfma_f32_16x16x32_bf16(a8[cur][s], bh[cur][nt], acc[s][nt], 0, 0, 0);
                acc[s][nt] = __builtin_amdgcn_mfma_f32_16x16x32_bf16(a8[cur][s], bl[cur][nt], acc[s][nt], 0, 0, 0);
            }
    }
#undef LOADA2
#undef LOADB2

#pragma unroll
    for (int s = 0; s < 2; s++)
        epi(acc[s], mh * 32 + s * 16, m0, q, lane, bias, attn, Zb, sbuf);
    __syncthreads();
    score_combine(sbuf, tid, m0, sS, sD);
}

// ---------------- segment softmax + weighted gather-sum + ELU ----------------
// one wave per dst node. Fast path: per-edge (src, alpha) in lane registers;
// phase C broadcasts via v_readlane (scalar pipe, no LDS), 16-deep MLP batches.

template <int OUT_BF>
__launch_bounds__(256)
__global__ void aggregate(const unsigned short* __restrict__ Zb,
                          const int* __restrict__ csr_src,
                          const int* __restrict__ offsets,
                          const float* __restrict__ sS,
                          const float* __restrict__ sD,
                          const float* __restrict__ ab,
                          unsigned short* __restrict__ OutBf,
                          float* __restrict__ OutF) {
    int v = blockIdx.x * 4 + (threadIdx.x >> 6);
    int lane = threadIdx.x & 63;
    int off = offsets[v];
    int deg = offsets[v + 1] - off;
    float sdv = sD[v] + ab[0];

    const unsigned int* Zrow = (const unsigned int*)Zb;  // dword = 2 bf16 dims
    float2 acc = {0.f, 0.f};

    if (deg <= 64) {
        bool act = lane < deg;
        int s_l = 0;
        float x = -3.0e38f;
        if (act) {
            s_l = csr_src[off + lane];
            x = lky(sS[s_l] + sdv);
        }
        float mx = x;
#pragma unroll
        for (int o = 32; o > 0; o >>= 1) mx = fmaxf(mx, __shfl_xor(mx, o, 64));
        float ex = act ? __expf(x - mx) : 0.f;
        float sum = ex;
#pragma unroll
        for (int o = 32; o > 0; o >>= 1) sum += __shfl_xor(sum, o, 64);
        float al_l = (deg > 0) ? ex / sum : 0.f;

        int t = 0;
        for (; t + 16 <= deg; t += 16) {
            int   s[16];
            float a[16];
            unsigned int rw[16];
#pragma unroll
            for (int j = 0; j < 16; j++) {
                s[j] = __builtin_amdgcn_readlane(s_l, t + j);
                a[j] = rl_f(al_l, t + j);
            }
#pragma unroll
            for (int j = 0; j < 16; j++)
                rw[j] = Zrow[(size_t)s[j] * (HID / 2) + lane];
#pragma unroll
            for (int j = 0; j < 16; j++) {
                float2 zz = bfu2(rw[j]);
                acc.x += a[j] * zz.x;
                acc.y += a[j] * zz.y;
            }
        }
        for (; t + 4 <= deg; t += 4) {
            int   s[4];
            float a[4];
            unsigned int rw[4];
#pragma unroll
            for (int j = 0; j < 4; j++) {
                s[j] = __builtin_amdgcn_readlane(s_l, t + j);
                a[j] = rl_f(al_l, t + j);
            }
#pragma unroll
            for (int j = 0; j < 4; j++)
                rw[j] = Zrow[(size_t)s[j] * (HID / 2) + lane];
#pragma unroll
            for (int j = 0; j < 4; j++) {
                float2 zz = bfu2(rw[j]);
                acc.x += a[j] * zz.x;
                acc.y += a[j] * zz.y;
            }
        }
        for (; t < deg; t++) {
            int sj = __builtin_amdgcn_readlane(s_l, t);
            float aj = rl_f(al_l, t);
            float2 zz = bfu2(Zrow[(size_t)sj * (HID / 2) + lane]);
            acc.x += aj * zz.x;
            acc.y += aj * zz.y;
        }
    } else {
        float mx = -3.0e38f;
        for (int t = lane; t < deg; t += 64) {
            int s = csr_src[off + t];
            mx = fmaxf(mx, lky(sS[s] + sdv));
        }
#pragma unroll
        for (int o = 32; o > 0; o >>= 1) mx = fmaxf(mx, __shfl_xor(mx, o, 64));
        float sum = 0.f;
        for (int t = lane; t < deg; t += 64) {
            int s = csr_src[off + t];
            sum += __expf(lky(sS[s] + sdv) - mx);
        }
#pragma unroll
        for (int o = 32; o > 0; o >>= 1) sum += __shfl_xor(sum, o, 64);
        float inv = 1.f / sum;
        for (int t = 0; t < deg; t++) {
            int s = csr_src[off + t];
            float al = __expf(lky(sS[s] + sdv) - mx) * inv;
            float2 zz = bfu2(Zrow[(size_t)s * (HID / 2) + lane]);
            acc.x += al * zz.x;
            acc.y += al * zz.y;
        }
    }

    acc.x = acc.x > 0.f ? acc.x : __expf(acc.x) - 1.f;
    acc.y = acc.y > 0.f ? acc.y : __expf(acc.y) - 1.f;

    if (OUT_BF) {
        ushort2 o2;
        o2.x = f2bf(acc.x);
        o2.y = f2bf(acc.y);
        *((ushort2*)(OutBf + (size_t)v * HID + lane * 2)) = o2;
    } else {
        float2 o2 = {acc.x, acc.y};
        *((float2*)(OutF + (size_t)v * HID + lane * 2)) = o2;
    }
}

// ---------------- launch ----------------

extern "C" void kernel_launch(void* const* d_in, const int* in_sizes, int n_in,
                              void* d_out, int out_size, void* d_ws, size_t ws_size,
                              hipStream_t stream) {
    const float* h   = (const float*)d_in[0];
    const int*   src = (const int*)d_in[1];
    const int*   dst = (const int*)d_in[2];
    const float* W1  = (const float*)d_in[3];
    const float* b1  = (const float*)d_in[4];
    const float* a1  = (const float*)d_in[5];
    const float* ab1 = (const float*)d_in[6];
    const float* W2  = (const float*)d_in[7];
    const float* b2  = (const float*)d_in[8];
    const float* a2  = (const float*)d_in[9];
    const float* ab2 = (const float*)d_in[10];
    float* out = (float*)d_out;

    // workspace carve-up (~34 MB)
    unsigned short* zb = (unsigned short*)d_ws;                 // 50000*128 bf16
    float* sS = (float*)(zb + (size_t)N_NODES * HID);           // 50000 f32
    float* sD = sS + N_NODES;                                   // 50000 f32
    int* counts  = (int*)(sD + N_NODES);                        // 50000
    int* offsets = counts + N_NODES;                            // 50001 (+pad)
    int* bsums   = offsets + N_NODES + 16;                      // 256
    unsigned short* h1   = (unsigned short*)(bsums + 256);      // 50000*128 bf16
    unsigned short* w1hi = h1 + (size_t)N_NODES * HID;          // 32768
    unsigned short* w1lo = w1hi + W1_ELEMS;
    unsigned short* w2hi = w1lo + W1_ELEMS;                     // 16384
    unsigned short* w2lo = w2hi + W2_ELEMS;
    int* csr_src = (int*)(w2lo + W2_ELEMS);                     // 800000
    int* erank   = csr_src + N_EDGES;                           // 800000

    hipMemsetAsync(counts, 0, (size_t)N_NODES * sizeof(int), stream);

    // CSR by dst + weight splits; hist returns each edge's in-bucket rank
    hist_split<<<EDGE_BLOCKS, 256, 0, stream>>>(dst, counts, erank,
                                                W1, w1hi, w1lo, W2, w2hi, w2lo);
    scan_block<<<SCAN_BLOCKS, 256, 0, stream>>>(counts, offsets, bsums);
    scan_add<<<SCAN_BLOCKS, 256, 0, stream>>>(offsets, bsums);
    fill_kernel<<<EDGE_BLOCKS, 256, 0, stream>>>(dst, src, erank, offsets, csr_src);

    // layer 1
    gemm_fc1<<<FC_BLOCKS, 256, 0, stream>>>(h, w1hi, w1lo, b1, a1, zb, sS, sD);
    aggregate<1><<<NODE_WBLKS, 256, 0, stream>>>(zb, csr_src, offsets, sS, sD, ab1, h1, nullptr);

    // layer 2
    gemm_fc2<<<FC_BLOCKS, 256, 0, stream>>>(h1, w2hi, w2lo, b2, a2, zb, sS, sD);
    aggregate<0><<<NODE_WBLKS, 256, 0, stream>>>(zb, csr_src, offsets, sS, sD, ab2, nullptr, out);
}

// Round 3
// 307.798 us; speedup vs baseline: 1.0179x; 1.0101x over previous
//
#include <hip/hip_runtime.h>
#include <hip/hip_bf16.h>

#define N_NODES 50000
#define N_EDGES 800000
#define IN_DIM  256
#define HID     128
#define LEAKY   0.01f

#define EDGE_BLOCKS  ((N_EDGES + 255) / 256)      // 3125
#define NODE_WBLKS   (N_NODES / 4)                // 12500
#define SCAN_BLOCKS  ((N_NODES + 255) / 256)      // 196
#define W1_ELEMS  (HID * IN_DIM)                  // 32768
#define W2_ELEMS  (HID * HID)                     // 16384

#define TM        64                              // GEMM rows per block
#define FC_BLOCKS ((N_NODES + TM - 1) / TM)       // 782

typedef __attribute__((ext_vector_type(8))) short short8;
typedef __attribute__((ext_vector_type(4))) float f32x4;

__device__ __forceinline__ unsigned short f2bf(float x) {
    union { __hip_bfloat16 b; unsigned short u; } c;
    c.b = __float2bfloat16(x);
    return c.u;
}
__device__ __forceinline__ float bf2f(unsigned short u) {
    union { unsigned int u; float f; } c;
    c.u = ((unsigned int)u) << 16;
    return c.f;
}
__device__ __forceinline__ float2 bfu2(unsigned int u) {
    float2 r;
    r.x = bf2f((unsigned short)(u & 0xffff));
    r.y = bf2f((unsigned short)(u >> 16));
    return r;
}
__device__ __forceinline__ float lky(float x) { return x > 0.f ? x : LEAKY * x; }
__device__ __forceinline__ float rl_f(float v, int l) {
    return __int_as_float(__builtin_amdgcn_readlane(__float_as_int(v), l));
}

// split 8 fp32 into bf16 hi/lo planes (same op order as LDS-staged original)
__device__ __forceinline__ void cvt8(const float4 v0, const float4 v1,
                                     short8& hi, short8& lo) {
    float f[8] = {v0.x, v0.y, v0.z, v0.w, v1.x, v1.y, v1.z, v1.w};
#pragma unroll
    for (int j = 0; j < 8; j++) {
        unsigned short h = f2bf(f[j]);
        hi[j] = (short)h;
        lo[j] = (short)f2bf(f[j] - bf2f(h));
    }
}

// ------- CSR hist (rank-returning) + W splits (fused, independent work) --------

__global__ void hist_split(const int* __restrict__ dst, int* __restrict__ counts,
                           int* __restrict__ erank,
                           const float* __restrict__ W1, unsigned short* __restrict__ w1hi,
                           unsigned short* __restrict__ w1lo,
                           const float* __restrict__ W2, unsigned short* __restrict__ w2hi,
                           unsigned short* __restrict__ w2lo) {
    int i = blockIdx.x * 256 + threadIdx.x;
    if (i < N_EDGES) erank[i] = atomicAdd(&counts[dst[i]], 1);
    if (i < W1_ELEMS) {
        float x = W1[i];
        unsigned short h = f2bf(x);
        w1hi[i] = h;
        w1lo[i] = f2bf(x - bf2f(h));
    } else if (i < W1_ELEMS + W2_ELEMS) {
        int j = i - W1_ELEMS;
        float x = W2[j];
        unsigned short h = f2bf(x);
        w2hi[j] = h;
        w2lo[j] = f2bf(x - bf2f(h));
    }
}

__global__ void scan_block(const int* __restrict__ counts, int* __restrict__ offsets,
                           int* __restrict__ bsums) {
    __shared__ int sh[256];
    int tid = threadIdx.x;
    int i = blockIdx.x * 256 + tid;
    int v = (i < N_NODES) ? counts[i] : 0;
    sh[tid] = v;
    __syncthreads();
    for (int o = 1; o < 256; o <<= 1) {
        int t = (tid >= o) ? sh[tid - o] : 0;
        __syncthreads();
        sh[tid] += t;
        __syncthreads();
    }
    if (i < N_NODES) offsets[i] = sh[tid] - v;
    if (tid == 255) bsums[blockIdx.x] = sh[255];
}

__global__ void scan_add(int* __restrict__ offsets, const int* __restrict__ bsums) {
    __shared__ int sh[256];
    int tid = threadIdx.x;
    int b = blockIdx.x;
    sh[tid] = (tid < b) ? bsums[tid] : 0;   // b <= 195 < 256
    __syncthreads();
    for (int o = 128; o > 0; o >>= 1) {
        if (tid < o) sh[tid] += sh[tid + o];
        __syncthreads();
    }
    int base = sh[0];
    int i = b * 256 + tid;
    if (i < N_NODES) offsets[i] += base;
    if (i == N_NODES) offsets[N_NODES] = N_EDGES;
}

// fill: atomic-free scatter; nontemporal store avoids cross-XCD L2 line bounce
__global__ void fill_kernel(const int* __restrict__ dst, const int* __restrict__ src,
                            const int* __restrict__ erank,
                            const int* __restrict__ offsets,
                            int* __restrict__ csr_src) {
    int i = blockIdx.x * 256 + threadIdx.x;
    if (i < N_EDGES) {
        int d = dst[i];
        int slot = offsets[d] + erank[i];
        __builtin_nontemporal_store(src[i], &csr_src[slot]);
    }
}

// ---------------- epilogue for one 16-row subtile ----------------
// C/D: col = lane&15, row = (lane>>4)*4 + reg. Partial scores reduce over r
// via shfl_xor, then land in sbuf[q*128 + {0:S,64:D} + lrow] for block-combine.

__device__ __forceinline__ void epi(const f32x4* accn, int lrow0, int m0, int q, int lane,
                                    const float* __restrict__ bias,
                                    const float* __restrict__ attn,
                                    unsigned short* __restrict__ Zb,
                                    float* __restrict__ sbuf) {
    int r = lane & 15;
    int lrowbase = lrow0 + (lane >> 4) * 4;   // 0..63 within block
    float ps[4] = {0.f, 0.f, 0.f, 0.f};
    float pd[4] = {0.f, 0.f, 0.f, 0.f};
#pragma unroll
    for (int nt = 0; nt < 4; nt++) {
        int n = q * 64 + nt * 16 + r;
        float bn = bias[n];
        float aS = attn[n];
        float aD = attn[HID + n];
#pragma unroll
        for (int reg = 0; reg < 4; reg++) {
            float zv = accn[nt][reg] + bn;
            if (m0 + lrowbase + reg < N_NODES)
                Zb[(size_t)(m0 + lrowbase + reg) * HID + n] = f2bf(zv);
            ps[reg] += zv * aS;
            pd[reg] += zv * aD;
        }
    }
#pragma unroll
    for (int o = 1; o < 16; o <<= 1) {
#pragma unroll
        for (int reg = 0; reg < 4; reg++) {
            ps[reg] += __shfl_xor(ps[reg], o, 64);
            pd[reg] += __shfl_xor(pd[reg], o, 64);
        }
    }
    if (r == 0) {
#pragma unroll
        for (int reg = 0; reg < 4; reg++) {
            sbuf[q * 128 + lrowbase + reg] = ps[reg];
            sbuf[q * 128 + 64 + lrowbase + reg] = pd[reg];
        }
    }
}

// combine q-halves and store single score planes
__device__ __forceinline__ void score_combine(const float* __restrict__ sbuf, int tid, int m0,
                                              float* __restrict__ sS, float* __restrict__ sD) {
    if (tid < TM) {
        int gr = m0 + tid;
        if (gr < N_NODES) {
            sS[gr] = sbuf[tid] + sbuf[128 + tid];
            sD[gr] = sbuf[64 + tid] + sbuf[128 + 64 + tid];
        }
    }
}

// ------- FC1: LDS-free, register-direct fragments, explicit 2-deep register
// double-buffer. amdgpu_waves_per_eu(3,3) pins the scheduler's occupancy
// target to what the grid delivers (782 blocks ~ 3 blocks/CU = 3 waves/EU),
// giving it a ~168-VGPR budget so the prefetch stays in registers instead of
// being crushed to a 60-VGPR serialized load-wait-use schedule. -------

__launch_bounds__(256) __attribute__((amdgpu_waves_per_eu(3, 3)))
__global__ void gemm_fc1(const float* __restrict__ A,
                         const unsigned short* __restrict__ Whi,
                         const unsigned short* __restrict__ Wlo,
                         const float* __restrict__ bias,
                         const float* __restrict__ attn,
                         unsigned short* __restrict__ Zb,
                         float* __restrict__ sS, float* __restrict__ sD) {
    __shared__ float sbuf[256];

    int tid  = threadIdx.x;
    int lane = tid & 63;
    int w    = tid >> 6;
    int q    = w & 1;
    int mh   = w >> 1;
    int m0   = blockIdx.x * TM;
    int r    = lane & 15;
    int koff = (lane >> 4) * 8;

    const float* Ap[2];
#pragma unroll
    for (int s = 0; s < 2; s++) {
        int gr = m0 + mh * 32 + s * 16 + r;
        if (gr >= N_NODES) gr = N_NODES - 1;
        Ap[s] = A + (size_t)gr * IN_DIM + koff;
    }
    const unsigned short* Bph = Whi + (size_t)(q * 64 + r) * IN_DIM + koff;
    const unsigned short* Bpl = Wlo + (size_t)(q * 64 + r) * IN_DIM + koff;

    f32x4 acc[2][4];
#pragma unroll
    for (int s = 0; s < 2; s++)
#pragma unroll
        for (int nt = 0; nt < 4; nt++) acc[s][nt] = (f32x4){0.f, 0.f, 0.f, 0.f};

    // register double-buffers (indices always compile-time constants)
    float4 av[2][2][2];            // [buf][s][half]
    short8 bh[2][4], bl[2][4];     // [buf][nt]

#define LOADA1(kt, pb)                                                      \
    {                                                                       \
        _Pragma("unroll") for (int s = 0; s < 2; s++) {                     \
            av[pb][s][0] = *(const float4*)(Ap[s] + (kt) * 32);             \
            av[pb][s][1] = *(const float4*)(Ap[s] + (kt) * 32 + 4);         \
        }                                                                   \
    }
#define LOADB1(kt, pb)                                                      \
    {                                                                       \
        _Pragma("unroll") for (int nt = 0; nt < 4; nt++) {                  \
            bh[pb][nt] = *(const short8*)(Bph + (size_t)nt * 16 * IN_DIM + (kt) * 32); \
            bl[pb][nt] = *(const short8*)(Bpl + (size_t)nt * 16 * IN_DIM + (kt) * 32); \
        }                                                                   \
    }

    LOADA1(0, 0);
    LOADB1(0, 0);

#pragma unroll
    for (int kt = 0; kt < IN_DIM / 32; kt++) {
        const int cur = kt & 1;
        const int nxt = cur ^ 1;
        if (kt < IN_DIM / 32 - 1) {
            LOADA1(kt + 1, nxt);
            LOADB1(kt + 1, nxt);
        }
        short8 ah[2], al[2];
#pragma unroll
        for (int s = 0; s < 2; s++) cvt8(av[cur][s][0], av[cur][s][1], ah[s], al[s]);
#pragma unroll
        for (int s = 0; s < 2; s++)
#pragma unroll
            for (int nt = 0; nt < 4; nt++) {
                acc[s][nt] = __builtin_amdgcn_mfma_f32_16x16x32_bf16(ah[s], bh[cur][nt], acc[s][nt], 0, 0, 0);
                acc[s][nt] = __builtin_amdgcn_mfma_f32_16x16x32_bf16(al[s], bh[cur][nt], acc[s][nt], 0, 0, 0);
                acc[s][nt] = __builtin_amdgcn_mfma_f32_16x16x32_bf16(ah[s], bl[cur][nt], acc[s][nt], 0, 0, 0);
            }
    }
#undef LOADA1
#undef LOADB1

#pragma unroll
    for (int s = 0; s < 2; s++)
        epi(acc[s], mh * 32 + s * 16, m0, q, lane, bias, attn, Zb, sbuf);
    __syncthreads();
    score_combine(sbuf, tid, m0, sS, sD);
}

// ------- FC2: same structure; A = h1 (single bf16 plane), W2 hi/lo. ----

__launch_bounds__(256) __attribute__((amdgpu_waves_per_eu(3, 3)))
__global__ void gemm_fc2(const unsigned short* __restrict__ Abf,
                         const unsigned short* __restrict__ Whi,
                         const unsigned short* __restrict__ Wlo,
                         const float* __restrict__ bias,
                         const float* __restrict__ attn,
                         unsigned short* __restrict__ Zb,
                         float* __restrict__ sS, float* __restrict__ sD) {
    __shared__ float sbuf[256];

    int tid  = threadIdx.x;
    int lane = tid & 63;
    int w    = tid >> 6;
    int q    = w & 1;
    int mh   = w >> 1;
    int m0   = blockIdx.x * TM;
    int r    = lane & 15;
    int koff = (lane >> 4) * 8;

    const unsigned short* Ap[2];
#pragma unroll
    for (int s = 0; s < 2; s++) {
        int gr = m0 + mh * 32 + s * 16 + r;
        if (gr >= N_NODES) gr = N_NODES - 1;
        Ap[s] = Abf + (size_t)gr * HID + koff;
    }
    const unsigned short* Bph = Whi + (size_t)(q * 64 + r) * HID + koff;
    const unsigned short* Bpl = Wlo + (size_t)(q * 64 + r) * HID + koff;

    f32x4 acc[2][4];
#pragma unroll
    for (int s = 0; s < 2; s++)
#pragma unroll
        for (int nt = 0; nt < 4; nt++) acc[s][nt] = (f32x4){0.f, 0.f, 0.f, 0.f};

    short8 a8[2][2];               // [buf][s]
    short8 bh[2][4], bl[2][4];     // [buf][nt]

#define LOADA2(kt, pb)                                                      \
    {                                                                       \
        _Pragma("unroll") for (int s = 0; s < 2; s++)                       \
            a8[pb][s] = *(const short8*)(Ap[s] + (kt) * 32);                \
    }
#define LOADB2(kt, pb)                                                      \
    {                                                                       \
        _Pragma("unroll") for (int nt = 0; nt < 4; nt++) {                  \
            bh[pb][nt] = *(const short8*)(Bph + (size_t)nt * 16 * HID + (kt) * 32); \
            bl[pb][nt] = *(const short8*)(Bpl + (size_t)nt * 16 * HID + (kt) * 32); \
        }                                                                   \
    }

    LOADA2(0, 0);
    LOADB2(0, 0);

#pragma unroll
    for (int kt = 0; kt < HID / 32; kt++) {
        const int cur = kt & 1;
        const int nxt = cur ^ 1;
        if (kt < HID / 32 - 1) {
            LOADA2(kt + 1, nxt);
            LOADB2(kt + 1, nxt);
        }
#pragma unroll
        for (int s = 0; s < 2; s++)
#pragma unroll
            for (int nt = 0; nt < 4; nt++) {
                acc[s][nt] = __builtin_amdgcn_mfma_f32_16x16x32_bf16(a8[cur][s], bh[cur][nt], acc[s][nt], 0, 0, 0);
                acc[s][nt] = __builtin_amdgcn_mfma_f32_16x16x32_bf16(a8[cur][s], bl[cur][nt], acc[s][nt], 0, 0, 0);
            }
    }
#undef LOADA2
#undef LOADB2

#pragma unroll
    for (int s = 0; s < 2; s++)
        epi(acc[s], mh * 32 + s * 16, m0, q, lane, bias, attn, Zb, sbuf);
    __syncthreads();
    score_combine(sbuf, tid, m0, sS, sD);
}

// ---------------- segment softmax + weighted gather-sum + ELU ----------------
// one wave per dst node. Fast path: per-edge (src, alpha) in lane registers;
// phase C broadcasts via v_readlane (scalar pipe, no LDS), 16-deep MLP batches.

template <int OUT_BF>
__launch_bounds__(256)
__global__ void aggregate(const unsigned short* __restrict__ Zb,
                          const int* __restrict__ csr_src,
                          const int* __restrict__ offsets,
                          const float* __restrict__ sS,
                          const float* __restrict__ sD,
                          const float* __restrict__ ab,
                          unsigned short* __restrict__ OutBf,
                          float* __restrict__ OutF) {
    int v = blockIdx.x * 4 + (threadIdx.x >> 6);
    int lane = threadIdx.x & 63;
    int off = offsets[v];
    int deg = offsets[v + 1] - off;
    float sdv = sD[v] + ab[0];

    const unsigned int* Zrow = (const unsigned int*)Zb;  // dword = 2 bf16 dims
    float2 acc = {0.f, 0.f};

    if (deg <= 64) {
        bool act = lane < deg;
        int s_l = 0;
        float x = -3.0e38f;
        if (act) {
            s_l = csr_src[off + lane];
            x = lky(sS[s_l] + sdv);
        }
        float mx = x;
#pragma unroll
        for (int o = 32; o > 0; o >>= 1) mx = fmaxf(mx, __shfl_xor(mx, o, 64));
        float ex = act ? __expf(x - mx) : 0.f;
        float sum = ex;
#pragma unroll
        for (int o = 32; o > 0; o >>= 1) sum += __shfl_xor(sum, o, 64);
        float al_l = (deg > 0) ? ex / sum : 0.f;

        int t = 0;
        for (; t + 16 <= deg; t += 16) {
            int   s[16];
            float a[16];
            unsigned int rw[16];
#pragma unroll
            for (int j = 0; j < 16; j++) {
                s[j] = __builtin_amdgcn_readlane(s_l, t + j);
                a[j] = rl_f(al_l, t + j);
            }
#pragma unroll
            for (int j = 0; j < 16; j++)
                rw[j] = Zrow[(size_t)s[j] * (HID / 2) + lane];
#pragma unroll
            for (int j = 0; j < 16; j++) {
                float2 zz = bfu2(rw[j]);
                acc.x += a[j] * zz.x;
                acc.y += a[j] * zz.y;
            }
        }
        for (; t + 4 <= deg; t += 4) {
            int   s[4];
            float a[4];
            unsigned int rw[4];
#pragma unroll
            for (int j = 0; j < 4; j++) {
                s[j] = __builtin_amdgcn_readlane(s_l, t + j);
                a[j] = rl_f(al_l, t + j);
            }
#pragma unroll
            for (int j = 0; j < 4; j++)
                rw[j] = Zrow[(size_t)s[j] * (HID / 2) + lane];
#pragma unroll
            for (int j = 0; j < 4; j++) {
                float2 zz = bfu2(rw[j]);
                acc.x += a[j] * zz.x;
                acc.y += a[j] * zz.y;
            }
        }
        for (; t < deg; t++) {
            int sj = __builtin_amdgcn_readlane(s_l, t);
            float aj = rl_f(al_l, t);
            float2 zz = bfu2(Zrow[(size_t)sj * (HID / 2) + lane]);
            acc.x += aj * zz.x;
            acc.y += aj * zz.y;
        }
    } else {
        float mx = -3.0e38f;
        for (int t = lane; t < deg; t += 64) {
            int s = csr_src[off + t];
            mx = fmaxf(mx, lky(sS[s] + sdv));
        }
#pragma unroll
        for (int o = 32; o > 0; o >>= 1) mx = fmaxf(mx, __shfl_xor(mx, o, 64));
        float sum = 0.f;
        for (int t = lane; t < deg; t += 64) {
            int s = csr_src[off + t];
            sum += __expf(lky(sS[s] + sdv) - mx);
        }
#pragma unroll
        for (int o = 32; o > 0; o >>= 1) sum += __shfl_xor(sum, o, 64);
        float inv = 1.f / sum;
        for (int t = 0; t < deg; t++) {
            int s = csr_src[off + t];
            float al = __expf(lky(sS[s] + sdv) - mx) * inv;
            float2 zz = bfu2(Zrow[(size_t)s * (HID / 2) + lane]);
            acc.x += al * zz.x;
            acc.y += al * zz.y;
        }
    }

    acc.x = acc.x > 0.f ? acc.x : __expf(acc.x) - 1.f;
    acc.y = acc.y > 0.f ? acc.y : __expf(acc.y) - 1.f;

    if (OUT_BF) {
        ushort2 o2;
        o2.x = f2bf(acc.x);
        o2.y = f2bf(acc.y);
        *((ushort2*)(OutBf + (size_t)v * HID + lane * 2)) = o2;
    } else {
        float2 o2 = {acc.x, acc.y};
        *((float2*)(OutF + (size_t)v * HID + lane * 2)) = o2;
    }
}

// ---------------- launch ----------------

extern "C" void kernel_launch(void* const* d_in, const int* in_sizes, int n_in,
                              void* d_out, int out_size, void* d_ws, size_t ws_size,
                              hipStream_t stream) {
    const float* h   = (const float*)d_in[0];
    const int*   src = (const int*)d_in[1];
    const int*   dst = (const int*)d_in[2];
    const float* W1  = (const float*)d_in[3];
    const float* b1  = (const float*)d_in[4];
    const float* a1  = (const float*)d_in[5];
    const float* ab1 = (const float*)d_in[6];
    const float* W2  = (const float*)d_in[7];
    const float* b2  = (const float*)d_in[8];
    const float* a2  = (const float*)d_in[9];
    const float* ab2 = (const float*)d_in[10];
    float* out = (float*)d_out;

    // workspace carve-up (~34 MB)
    unsigned short* zb = (unsigned short*)d_ws;                 // 50000*128 bf16
    float* sS = (float*)(zb + (size_t)N_NODES * HID);           // 50000 f32
    float* sD = sS + N_NODES;                                   // 50000 f32
    int* counts  = (int*)(sD + N_NODES);                        // 50000
    int* offsets = counts + N_NODES;                            // 50001 (+pad)
    int* bsums   = offsets + N_NODES + 16;                      // 256
    unsigned short* h1   = (unsigned short*)(bsums + 256);      // 50000*128 bf16
    unsigned short* w1hi = h1 + (size_t)N_NODES * HID;          // 32768
    unsigned short* w1lo = w1hi + W1_ELEMS;
    unsigned short* w2hi = w1lo + W1_ELEMS;                     // 16384
    unsigned short* w2lo = w2hi + W2_ELEMS;
    int* csr_src = (int*)(w2lo + W2_ELEMS);                     // 800000
    int* erank   = csr_src + N_EDGES;                           // 800000

    hipMemsetAsync(counts, 0, (size_t)N_NODES * sizeof(int), stream);

    // CSR by dst + weight splits; hist returns each edge's in-bucket rank
    hist_split<<<EDGE_BLOCKS, 256, 0, stream>>>(dst, counts, erank,
                                                W1, w1hi, w1lo, W2, w2hi, w2lo);
    scan_block<<<SCAN_BLOCKS, 256, 0, stream>>>(counts, offsets, bsums);
    scan_add<<<SCAN_BLOCKS, 256, 0, stream>>>(offsets, bsums);
    fill_kernel<<<EDGE_BLOCKS, 256, 0, stream>>>(dst, src, erank, offsets, csr_src);

    // layer 1
    gemm_fc1<<<FC_BLOCKS, 256, 0, stream>>>(h, w1hi, w1lo, b1, a1, zb, sS, sD);
    aggregate<1><<<NODE_WBLKS, 256, 0, stream>>>(zb, csr_src, offsets, sS, sD, ab1, h1, nullptr);

    // layer 2
    gemm_fc2<<<FC_BLOCKS, 256, 0, stream>>>(h1, w2hi, w2lo, b2, a2, zb, sS, sD);
    aggregate<0><<<NODE_WBLKS, 256, 0, stream>>>(zb, csr_src, offsets, sS, sD, ab2, nullptr, out);
}

// Round 4
// 287.609 us; speedup vs baseline: 1.0894x; 1.0702x over previous
//
#include <hip/hip_runtime.h>
#include <hip/hip_bf16.h>

#define N_NODES 50000
#define N_EDGES 800000
#define IN_DIM  256
#define HID     128
#define LEAKY   0.01f

#define EDGE_BLOCKS  ((N_EDGES + 255) / 256)      // 3125
#define NODE_WBLKS   (N_NODES / 4)                // 12500
#define SCAN_BLOCKS  ((N_NODES + 255) / 256)      // 196
#define W1_ELEMS  (HID * IN_DIM)                  // 32768
#define W2_ELEMS  (HID * HID)                     // 16384

#define TM        64                              // GEMM rows per block
#define FC_BLOCKS ((N_NODES + TM - 1) / TM)       // 782

typedef __attribute__((ext_vector_type(8))) short short8;
typedef __attribute__((ext_vector_type(4))) float f32x4;

// async global->LDS, 16B per lane; dest = wave-uniform base + lane*16 (m97 pattern)
#define GLDS(g, l)                                                              \
    __builtin_amdgcn_global_load_lds(                                           \
        (const __attribute__((address_space(1))) void*)(g),                     \
        (__attribute__((address_space(3))) void*)(l), 16, 0, 0)

__device__ __forceinline__ unsigned short f2bf(float x) {
    union { __hip_bfloat16 b; unsigned short u; } c;
    c.b = __float2bfloat16(x);
    return c.u;
}
__device__ __forceinline__ float bf2f(unsigned short u) {
    union { unsigned int u; float f; } c;
    c.u = ((unsigned int)u) << 16;
    return c.f;
}
__device__ __forceinline__ float2 bfu2(unsigned int u) {
    float2 r;
    r.x = bf2f((unsigned short)(u & 0xffff));
    r.y = bf2f((unsigned short)(u >> 16));
    return r;
}
__device__ __forceinline__ float lky(float x) { return x > 0.f ? x : LEAKY * x; }
__device__ __forceinline__ float rl_f(float v, int l) {
    return __int_as_float(__builtin_amdgcn_readlane(__float_as_int(v), l));
}

// split 8 fp32 into bf16 hi/lo (same op order as original -> identical numerics)
__device__ __forceinline__ void cvt8(const float4 v0, const float4 v1,
                                     short8& hi, short8& lo) {
    float f[8] = {v0.x, v0.y, v0.z, v0.w, v1.x, v1.y, v1.z, v1.w};
#pragma unroll
    for (int j = 0; j < 8; j++) {
        unsigned short h = f2bf(f[j]);
        hi[j] = (short)h;
        lo[j] = (short)f2bf(f[j] - bf2f(h));
    }
}

// ------- CSR hist (rank-returning) + W splits (fused, independent work) --------

__global__ void hist_split(const int* __restrict__ dst, int* __restrict__ counts,
                           int* __restrict__ erank,
                           const float* __restrict__ W1, unsigned short* __restrict__ w1hi,
                           unsigned short* __restrict__ w1lo,
                           const float* __restrict__ W2, unsigned short* __restrict__ w2hi,
                           unsigned short* __restrict__ w2lo) {
    int i = blockIdx.x * 256 + threadIdx.x;
    if (i < N_EDGES) erank[i] = atomicAdd(&counts[dst[i]], 1);
    if (i < W1_ELEMS) {
        float x = W1[i];
        unsigned short h = f2bf(x);
        w1hi[i] = h;
        w1lo[i] = f2bf(x - bf2f(h));
    } else if (i < W1_ELEMS + W2_ELEMS) {
        int j = i - W1_ELEMS;
        float x = W2[j];
        unsigned short h = f2bf(x);
        w2hi[j] = h;
        w2lo[j] = f2bf(x - bf2f(h));
    }
}

__global__ void scan_block(const int* __restrict__ counts, int* __restrict__ offsets,
                           int* __restrict__ bsums) {
    __shared__ int sh[256];
    int tid = threadIdx.x;
    int i = blockIdx.x * 256 + tid;
    int v = (i < N_NODES) ? counts[i] : 0;
    sh[tid] = v;
    __syncthreads();
    for (int o = 1; o < 256; o <<= 1) {
        int t = (tid >= o) ? sh[tid - o] : 0;
        __syncthreads();
        sh[tid] += t;
        __syncthreads();
    }
    if (i < N_NODES) offsets[i] = sh[tid] - v;
    if (tid == 255) bsums[blockIdx.x] = sh[255];
}

__global__ void scan_add(int* __restrict__ offsets, const int* __restrict__ bsums) {
    __shared__ int sh[256];
    int tid = threadIdx.x;
    int b = blockIdx.x;
    sh[tid] = (tid < b) ? bsums[tid] : 0;   // b <= 195 < 256
    __syncthreads();
    for (int o = 128; o > 0; o >>= 1) {
        if (tid < o) sh[tid] += sh[tid + o];
        __syncthreads();
    }
    int base = sh[0];
    int i = b * 256 + tid;
    if (i < N_NODES) offsets[i] += base;
    if (i == N_NODES) offsets[N_NODES] = N_EDGES;
}

// fill: atomic-free scatter; nontemporal store avoids cross-XCD L2 line bounce
__global__ void fill_kernel(const int* __restrict__ dst, const int* __restrict__ src,
                            const int* __restrict__ erank,
                            const int* __restrict__ offsets,
                            int* __restrict__ csr_src) {
    int i = blockIdx.x * 256 + threadIdx.x;
    if (i < N_EDGES) {
        int d = dst[i];
        int slot = offsets[d] + erank[i];
        __builtin_nontemporal_store(src[i], &csr_src[slot]);
    }
}

// ---------------- epilogue for one 16-row subtile ----------------
// C/D: col = lane&15, row = (lane>>4)*4 + reg. Partial scores reduce over r
// via shfl_xor, then land in sbuf[q*128 + {0:S,64:D} + lrow] for block-combine.

__device__ __forceinline__ void epi(const f32x4* accn, int lrow0, int m0, int q, int lane,
                                    const float* __restrict__ bias,
                                    const float* __restrict__ attn,
                                    unsigned short* __restrict__ Zb,
                                    float* __restrict__ sbuf) {
    int r = lane & 15;
    int lrowbase = lrow0 + (lane >> 4) * 4;   // 0..63 within block
    float ps[4] = {0.f, 0.f, 0.f, 0.f};
    float pd[4] = {0.f, 0.f, 0.f, 0.f};
#pragma unroll
    for (int nt = 0; nt < 4; nt++) {
        int n = q * 64 + nt * 16 + r;
        float bn = bias[n];
        float aS = attn[n];
        float aD = attn[HID + n];
#pragma unroll
        for (int reg = 0; reg < 4; reg++) {
            float zv = accn[nt][reg] + bn;
            if (m0 + lrowbase + reg < N_NODES)
                Zb[(size_t)(m0 + lrowbase + reg) * HID + n] = f2bf(zv);
            ps[reg] += zv * aS;
            pd[reg] += zv * aD;
        }
    }
#pragma unroll
    for (int o = 1; o < 16; o <<= 1) {
#pragma unroll
        for (int reg = 0; reg < 4; reg++) {
            ps[reg] += __shfl_xor(ps[reg], o, 64);
            pd[reg] += __shfl_xor(pd[reg], o, 64);
        }
    }
    if (r == 0) {
#pragma unroll
        for (int reg = 0; reg < 4; reg++) {
            sbuf[q * 128 + lrowbase + reg] = ps[reg];
            sbuf[q * 128 + 64 + lrowbase + reg] = pd[reg];
        }
    }
}

// combine q-halves and store single score planes
__device__ __forceinline__ void score_combine(const float* __restrict__ sbuf, int tid, int m0,
                                              float* __restrict__ sS, float* __restrict__ sD) {
    if (tid < TM) {
        int gr = m0 + tid;
        if (gr < N_NODES) {
            sS[gr] = sbuf[tid] + sbuf[128 + tid];
            sD[gr] = sbuf[64 + tid] + sbuf[128 + 64 + tid];
        }
    }
}

// ------- FC1: global_load_lds staging into fragment-order LDS. -------
// LDS tile per K-step(32): 24 chunks x 1KB. Chunk = one wave-wide async load
// (lane l -> bytes [16l,16l+16)). Chunk layout IS fragment order:
//   c in [0,8):  A fp32, c = 2*S + half; slot l = A[m0+S*16+(l&15)][k0+(l>>4)*8+4*half ..+3]
//   c in [8,16): B-hi,  c-8  = col-subtile nt; slot l = W[(nt*16+(l&15))][k0+(l>>4)*8 ..+7]
//   c in [16,24): B-lo, likewise.
// => every global source is 16B-contiguous, every ds_read_b128 is lane-stride-16B
// (zero bank conflicts), staging consumes no VGPRs so the scheduler cannot
// serialize it (rounds 1-3 post-mortem). 2-phase double-buffer, one barrier/step.

__launch_bounds__(256)
__global__ void gemm_fc1(const float* __restrict__ A,
                         const unsigned short* __restrict__ Whi,
                         const unsigned short* __restrict__ Wlo,
                         const float* __restrict__ bias,
                         const float* __restrict__ attn,
                         unsigned short* __restrict__ Zb,
                         float* __restrict__ sS, float* __restrict__ sD) {
    __shared__ char lds[2][24576];

    int tid  = threadIdx.x;
    int lane = tid & 63;
    int w    = tid >> 6;
    int q    = w & 1;
    int mh   = w >> 1;
    int m0   = blockIdx.x * TM;
    int r    = lane & 15;
    int kg   = lane >> 4;

    // 6 staging chunks per wave: c = 6w + j
    const char* gp[6];
    int gstep[6];
    int loff[6];
#pragma unroll
    for (int j = 0; j < 6; j++) {
        int c = w * 6 + j;
        loff[j] = c * 1024;
        if (c < 8) {
            int S = c >> 1, hh = c & 1;
            int row = m0 + S * 16 + r;
            if (row >= N_NODES) row = N_NODES - 1;
            gp[j] = (const char*)(A + (size_t)row * IN_DIM + kg * 8 + hh * 4);
            gstep[j] = 32 * 4;
        } else if (c < 16) {
            int nt = c - 8;
            gp[j] = (const char*)(Whi + (size_t)(nt * 16 + r) * IN_DIM + kg * 8);
            gstep[j] = 32 * 2;
        } else {
            int nt = c - 16;
            gp[j] = (const char*)(Wlo + (size_t)(nt * 16 + r) * IN_DIM + kg * 8);
            gstep[j] = 32 * 2;
        }
    }

#define STAGE1(b)                                                   \
    {                                                               \
        _Pragma("unroll") for (int j = 0; j < 6; j++) {             \
            GLDS(gp[j], lds[b] + loff[j]);                          \
            gp[j] += gstep[j];                                      \
        }                                                           \
    }

    f32x4 acc[2][4];
#pragma unroll
    for (int s = 0; s < 2; s++)
#pragma unroll
        for (int nt = 0; nt < 4; nt++) acc[s][nt] = (f32x4){0.f, 0.f, 0.f, 0.f};

    STAGE1(0);
    __syncthreads();                       // implicit vmcnt(0) drains the stage

#pragma unroll
    for (int kt = 0; kt < IN_DIM / 32; kt++) {
        const int cur = kt & 1;
        if (kt < IN_DIM / 32 - 1) STAGE1(cur ^ 1);   // async prefetch next step

        const float* Af = (const float*)lds[cur];
        const unsigned short* Bh = (const unsigned short*)(lds[cur] + 8192);
        const unsigned short* Bl = (const unsigned short*)(lds[cur] + 16384);

        short8 ah[2], al[2], bh[4], bl[4];
#pragma unroll
        for (int s = 0; s < 2; s++) {
            int S = mh * 2 + s;
            float4 v0 = *(const float4*)(Af + (S * 2 + 0) * 256 + lane * 4);
            float4 v1 = *(const float4*)(Af + (S * 2 + 1) * 256 + lane * 4);
            cvt8(v0, v1, ah[s], al[s]);
        }
#pragma unroll
        for (int nt = 0; nt < 4; nt++) {
            bh[nt] = *(const short8*)(Bh + (q * 4 + nt) * 512 + lane * 8);
            bl[nt] = *(const short8*)(Bl + (q * 4 + nt) * 512 + lane * 8);
        }
#pragma unroll
        for (int s = 0; s < 2; s++)
#pragma unroll
            for (int nt = 0; nt < 4; nt++) {
                acc[s][nt] = __builtin_amdgcn_mfma_f32_16x16x32_bf16(ah[s], bh[nt], acc[s][nt], 0, 0, 0);
                acc[s][nt] = __builtin_amdgcn_mfma_f32_16x16x32_bf16(al[s], bh[nt], acc[s][nt], 0, 0, 0);
                acc[s][nt] = __builtin_amdgcn_mfma_f32_16x16x32_bf16(ah[s], bl[nt], acc[s][nt], 0, 0, 0);
            }
        __syncthreads();                   // drains prefetch + guards buffer swap
    }
#undef STAGE1

    float* sbuf = (float*)lds[0];
#pragma unroll
    for (int s = 0; s < 2; s++)
        epi(acc[s], mh * 32 + s * 16, m0, q, lane, bias, attn, Zb, sbuf);
    __syncthreads();
    score_combine(sbuf, tid, m0, sS, sD);
}

// ------- FC2: same structure; A = h1 bf16 plane (no conversion), K=128. ----
// 20 chunks x 1KB per K-step(32): c<4: A (S=c); c in[4,12): B-hi; [12,20): B-lo.

__launch_bounds__(256)
__global__ void gemm_fc2(const unsigned short* __restrict__ Abf,
                         const unsigned short* __restrict__ Whi,
                         const unsigned short* __restrict__ Wlo,
                         const float* __restrict__ bias,
                         const float* __restrict__ attn,
                         unsigned short* __restrict__ Zb,
                         float* __restrict__ sS, float* __restrict__ sD) {
    __shared__ char lds[2][20480];

    int tid  = threadIdx.x;
    int lane = tid & 63;
    int w    = tid >> 6;
    int q    = w & 1;
    int mh   = w >> 1;
    int m0   = blockIdx.x * TM;
    int r    = lane & 15;
    int kg   = lane >> 4;

    // 5 staging chunks per wave: c = 5w + j (all strides 64B)
    const char* gp[5];
    int loff[5];
#pragma unroll
    for (int j = 0; j < 5; j++) {
        int c = w * 5 + j;
        loff[j] = c * 1024;
        if (c < 4) {
            int row = m0 + c * 16 + r;
            if (row >= N_NODES) row = N_NODES - 1;
            gp[j] = (const char*)(Abf + (size_t)row * HID + kg * 8);
        } else if (c < 12) {
            gp[j] = (const char*)(Whi + (size_t)((c - 4) * 16 + r) * HID + kg * 8);
        } else {
            gp[j] = (const char*)(Wlo + (size_t)((c - 12) * 16 + r) * HID + kg * 8);
        }
    }

#define STAGE2(b)                                                   \
    {                                                               \
        _Pragma("unroll") for (int j = 0; j < 5; j++) {             \
            GLDS(gp[j], lds[b] + loff[j]);                          \
            gp[j] += 64;                                            \
        }                                                           \
    }

    f32x4 acc[2][4];
#pragma unroll
    for (int s = 0; s < 2; s++)
#pragma unroll
        for (int nt = 0; nt < 4; nt++) acc[s][nt] = (f32x4){0.f, 0.f, 0.f, 0.f};

    STAGE2(0);
    __syncthreads();

#pragma unroll
    for (int kt = 0; kt < HID / 32; kt++) {
        const int cur = kt & 1;
        if (kt < HID / 32 - 1) STAGE2(cur ^ 1);

        const unsigned short* Aq = (const unsigned short*)lds[cur];
        const unsigned short* Bh = (const unsigned short*)(lds[cur] + 4096);
        const unsigned short* Bl = (const unsigned short*)(lds[cur] + 12288);

        short8 a8[2], bh[4], bl[4];
#pragma unroll
        for (int s = 0; s < 2; s++)
            a8[s] = *(const short8*)(Aq + (mh * 2 + s) * 512 + lane * 8);
#pragma unroll
        for (int nt = 0; nt < 4; nt++) {
            bh[nt] = *(const short8*)(Bh + (q * 4 + nt) * 512 + lane * 8);
            bl[nt] = *(const short8*)(Bl + (q * 4 + nt) * 512 + lane * 8);
        }
#pragma unroll
        for (int s = 0; s < 2; s++)
#pragma unroll
            for (int nt = 0; nt < 4; nt++) {
                acc[s][nt] = __builtin_amdgcn_mfma_f32_16x16x32_bf16(a8[s], bh[nt], acc[s][nt], 0, 0, 0);
                acc[s][nt] = __builtin_amdgcn_mfma_f32_16x16x32_bf16(a8[s], bl[nt], acc[s][nt], 0, 0, 0);
            }
        __syncthreads();
    }
#undef STAGE2

    float* sbuf = (float*)lds[0];
#pragma unroll
    for (int s = 0; s < 2; s++)
        epi(acc[s], mh * 32 + s * 16, m0, q, lane, bias, attn, Zb, sbuf);
    __syncthreads();
    score_combine(sbuf, tid, m0, sS, sD);
}

// ---------------- segment softmax + weighted gather-sum + ELU ----------------
// one wave per dst node. Fast path: per-edge (src, alpha) in lane registers;
// phase C broadcasts via v_readlane (scalar pipe, no LDS), 16-deep MLP batches.

template <int OUT_BF>
__launch_bounds__(256)
__global__ void aggregate(const unsigned short* __restrict__ Zb,
                          const int* __restrict__ csr_src,
                          const int* __restrict__ offsets,
                          const float* __restrict__ sS,
                          const float* __restrict__ sD,
                          const float* __restrict__ ab,
                          unsigned short* __restrict__ OutBf,
                          float* __restrict__ OutF) {
    int v = blockIdx.x * 4 + (threadIdx.x >> 6);
    int lane = threadIdx.x & 63;
    int off = offsets[v];
    int deg = offsets[v + 1] - off;
    float sdv = sD[v] + ab[0];

    const unsigned int* Zrow = (const unsigned int*)Zb;  // dword = 2 bf16 dims
    float2 acc = {0.f, 0.f};

    if (deg <= 64) {
        bool act = lane < deg;
        int s_l = 0;
        float x = -3.0e38f;
        if (act) {
            s_l = csr_src[off + lane];
            x = lky(sS[s_l] + sdv);
        }
        float mx = x;
#pragma unroll
        for (int o = 32; o > 0; o >>= 1) mx = fmaxf(mx, __shfl_xor(mx, o, 64));
        float ex = act ? __expf(x - mx) : 0.f;
        float sum = ex;
#pragma unroll
        for (int o = 32; o > 0; o >>= 1) sum += __shfl_xor(sum, o, 64);
        float al_l = (deg > 0) ? ex / sum : 0.f;

        int t = 0;
        for (; t + 16 <= deg; t += 16) {
            int   s[16];
            float a[16];
            unsigned int rw[16];
#pragma unroll
            for (int j = 0; j < 16; j++) {
                s[j] = __builtin_amdgcn_readlane(s_l, t + j);
                a[j] = rl_f(al_l, t + j);
            }
#pragma unroll
            for (int j = 0; j < 16; j++)
                rw[j] = Zrow[(size_t)s[j] * (HID / 2) + lane];
#pragma unroll
            for (int j = 0; j < 16; j++) {
                float2 zz = bfu2(rw[j]);
                acc.x += a[j] * zz.x;
                acc.y += a[j] * zz.y;
            }
        }
        for (; t + 4 <= deg; t += 4) {
            int   s[4];
            float a[4];
            unsigned int rw[4];
#pragma unroll
            for (int j = 0; j < 4; j++) {
                s[j] = __builtin_amdgcn_readlane(s_l, t + j);
                a[j] = rl_f(al_l, t + j);
            }
#pragma unroll
            for (int j = 0; j < 4; j++)
                rw[j] = Zrow[(size_t)s[j] * (HID / 2) + lane];
#pragma unroll
            for (int j = 0; j < 4; j++) {
                float2 zz = bfu2(rw[j]);
                acc.x += a[j] * zz.x;
                acc.y += a[j] * zz.y;
            }
        }
        for (; t < deg; t++) {
            int sj = __builtin_amdgcn_readlane(s_l, t);
            float aj = rl_f(al_l, t);
            float2 zz = bfu2(Zrow[(size_t)sj * (HID / 2) + lane]);
            acc.x += aj * zz.x;
            acc.y += aj * zz.y;
        }
    } else {
        float mx = -3.0e38f;
        for (int t = lane; t < deg; t += 64) {
            int s = csr_src[off + t];
            mx = fmaxf(mx, lky(sS[s] + sdv));
        }
#pragma unroll
        for (int o = 32; o > 0; o >>= 1) mx = fmaxf(mx, __shfl_xor(mx, o, 64));
        float sum = 0.f;
        for (int t = lane; t < deg; t += 64) {
            int s = csr_src[off + t];
            sum += __expf(lky(sS[s] + sdv) - mx);
        }
#pragma unroll
        for (int o = 32; o > 0; o >>= 1) sum += __shfl_xor(sum, o, 64);
        float inv = 1.f / sum;
        for (int t = 0; t < deg; t++) {
            int s = csr_src[off + t];
            float al = __expf(lky(sS[s] + sdv) - mx) * inv;
            float2 zz = bfu2(Zrow[(size_t)s * (HID / 2) + lane]);
            acc.x += al * zz.x;
            acc.y += al * zz.y;
        }
    }

    acc.x = acc.x > 0.f ? acc.x : __expf(acc.x) - 1.f;
    acc.y = acc.y > 0.f ? acc.y : __expf(acc.y) - 1.f;

    if (OUT_BF) {
        ushort2 o2;
        o2.x = f2bf(acc.x);
        o2.y = f2bf(acc.y);
        *((ushort2*)(OutBf + (size_t)v * HID + lane * 2)) = o2;
    } else {
        float2 o2 = {acc.x, acc.y};
        *((float2*)(OutF + (size_t)v * HID + lane * 2)) = o2;
    }
}

// ---------------- launch ----------------

extern "C" void kernel_launch(void* const* d_in, const int* in_sizes, int n_in,
                              void* d_out, int out_size, void* d_ws, size_t ws_size,
                              hipStream_t stream) {
    const float* h   = (const float*)d_in[0];
    const int*   src = (const int*)d_in[1];
    const int*   dst = (const int*)d_in[2];
    const float* W1  = (const float*)d_in[3];
    const float* b1  = (const float*)d_in[4];
    const float* a1  = (const float*)d_in[5];
    const float* ab1 = (const float*)d_in[6];
    const float* W2  = (const float*)d_in[7];
    const float* b2  = (const float*)d_in[8];
    const float* a2  = (const float*)d_in[9];
    const float* ab2 = (const float*)d_in[10];
    float* out = (float*)d_out;

    // workspace carve-up (~34 MB)
    unsigned short* zb = (unsigned short*)d_ws;                 // 50000*128 bf16
    float* sS = (float*)(zb + (size_t)N_NODES * HID);           // 50000 f32
    float* sD = sS + N_NODES;                                   // 50000 f32
    int* counts  = (int*)(sD + N_NODES);                        // 50000
    int* offsets = counts + N_NODES;                            // 50001 (+pad)
    int* bsums   = offsets + N_NODES + 16;                      // 256
    unsigned short* h1   = (unsigned short*)(bsums + 256);      // 50000*128 bf16
    unsigned short* w1hi = h1 + (size_t)N_NODES * HID;          // 32768
    unsigned short* w1lo = w1hi + W1_ELEMS;
    unsigned short* w2hi = w1lo + W1_ELEMS;                     // 16384
    unsigned short* w2lo = w2hi + W2_ELEMS;
    int* csr_src = (int*)(w2lo + W2_ELEMS);                     // 800000
    int* erank   = csr_src + N_EDGES;                           // 800000

    hipMemsetAsync(counts, 0, (size_t)N_NODES * sizeof(int), stream);

    // CSR by dst + weight splits; hist returns each edge's in-bucket rank
    hist_split<<<EDGE_BLOCKS, 256, 0, stream>>>(dst, counts, erank,
                                                W1, w1hi, w1lo, W2, w2hi, w2lo);
    scan_block<<<SCAN_BLOCKS, 256, 0, stream>>>(counts, offsets, bsums);
    scan_add<<<SCAN_BLOCKS, 256, 0, stream>>>(offsets, bsums);
    fill_kernel<<<EDGE_BLOCKS, 256, 0, stream>>>(dst, src, erank, offsets, csr_src);

    // layer 1
    gemm_fc1<<<FC_BLOCKS, 256, 0, stream>>>(h, w1hi, w1lo, b1, a1, zb, sS, sD);
    aggregate<1><<<NODE_WBLKS, 256, 0, stream>>>(zb, csr_src, offsets, sS, sD, ab1, h1, nullptr);

    // layer 2
    gemm_fc2<<<FC_BLOCKS, 256, 0, stream>>>(h1, w2hi, w2lo, b2, a2, zb, sS, sD);
    aggregate<0><<<NODE_WBLKS, 256, 0, stream>>>(zb, csr_src, offsets, sS, sD, ab2, nullptr, out);
}